// Round 1
// baseline (2658.829 us; speedup 1.0000x reference)
//
#include <hip/hip_runtime.h>

#define TT   1024   // timesteps
#define BATCH 2048
#define NI   6      // input dim
#define NH   38     // hidden
#define NG   152    // 4*NH
#define NCLS 8      // classes
#define NB   8      // batches per block
#define HP   40     // padded hidden row (16B-aligned float4 rows)
#define BLK  512

__device__ __forceinline__ float fsig(float v) {
    return __fdividef(1.0f, 1.0f + __expf(-v));
}
__device__ __forceinline__ float ftanh(float v) {
    // tanh(x) = 1 - 2/(1+e^{2x}); saturates correctly at +-inf
    return 1.0f - __fdividef(2.0f, 1.0f + __expf(2.0f * v));
}

__global__ __launch_bounds__(BLK, 2) void lstm2_kernel(
    const float* __restrict__ x,
    const float* __restrict__ Wih0, const float* __restrict__ Whh0, const float* __restrict__ b0,
    const float* __restrict__ Wih1, const float* __restrict__ Whh1, const float* __restrict__ b1,
    const float* __restrict__ Wc,   const float* __restrict__ bc,
    float* __restrict__ out)
{
    __shared__ __align__(16) float h1buf[2][NB][HP];
    __shared__ __align__(16) float h2buf[2][NB][HP];
    __shared__ float qbuf[NB][NG];        // Whh1 @ h2(t-1) partials
    __shared__ float xbuf[2][NB][NI];     // double-buffered x_t staging

    const int tid   = threadIdx.x;
    const int bbase = blockIdx.x * NB;

    // zero the h state buffers (both slots; t=0 reads slot 1)
    for (int idx = tid; idx < 2 * NB * HP; idx += BLK) {
        (&h1buf[0][0][0])[idx] = 0.0f;
        (&h2buf[0][0][0])[idx] = 0.0f;
    }
    // preload x(t=0) into slot 0
    if (tid < NB * NI) {
        const int b = tid / NI, i = tid % NI;
        xbuf[0][b][i] = x[((size_t)(bbase + b) * TT + 0) * NI + i];
    }

    // roles: 0 = layer1 (matvec+pointwise), 1 = layer2 p-side (Wih1 + combine + pointwise),
    //        2 = layer2 q-side (Whh1 @ h2prev), 3 = x prefetch, 4 = idle
    int role, u = 0, bp = 0;
    if      (tid < NG)              { role = 0; u = tid % NH;            bp = tid / NH; }
    else if (tid < 2 * NG)          { role = 1; u = (tid - NG) % NH;     bp = (tid - NG) / NH; }
    else if (tid < 3 * NG)          { role = 2; u = (tid - 2*NG) % NH;   bp = (tid - 2*NG) / NH; }
    else if (tid < 3*NG + NB*NI)    { role = 3; }
    else                            { role = 4; }

    // register-resident weights: 4 gate rows (i,f,g,o) of one hidden unit.
    // shared array across roles so allocation is unified (~220 VGPR total).
    float w[4][NH];        // role0: Whh0 rows, role1: Wih1 rows, role2: Whh1 rows
    float wx[4][NI];       // role0 only: Wih0 rows
    float bias[4] = {0.f, 0.f, 0.f, 0.f};
    float cst[2]  = {0.f, 0.f};   // role0: c1 for 2 batches; role1: c2

    if (role <= 2) {
        const float* Wm = (role == 0) ? Whh0 : (role == 1) ? Wih1 : Whh1;
        #pragma unroll
        for (int g = 0; g < 4; ++g) {
            const float* row = Wm + (size_t)(u + g * NH) * NH;
            #pragma unroll
            for (int k = 0; k < NH; ++k) w[g][k] = row[k];
        }
    }
    if (role == 0) {
        #pragma unroll
        for (int g = 0; g < 4; ++g) {
            const float* row = Wih0 + (size_t)(u + g * NH) * NI;
            #pragma unroll
            for (int i = 0; i < NI; ++i) wx[g][i] = row[i];
            bias[g] = b0[u + g * NH];
        }
    } else if (role == 1) {
        #pragma unroll
        for (int g = 0; g < 4; ++g) bias[g] = b1[u + g * NH];
    }

    __syncthreads();

    #pragma unroll 1
    for (int t = 0; t < TT; ++t) {
        const int cur = t & 1, prv = cur ^ 1;

        // ---------------- phase 1 ----------------
        if (role == 0) {
            // layer 1: g = b0 + Wih0 x_t + Whh0 h1(t-1); then pointwise
            float acc[2][4];
            #pragma unroll
            for (int bb2 = 0; bb2 < 2; ++bb2) {
                const int b = bp * 2 + bb2;
                #pragma unroll
                for (int g = 0; g < 4; ++g) acc[bb2][g] = bias[g];
                #pragma unroll
                for (int i = 0; i < NI; ++i) {
                    const float xv = xbuf[cur][b][i];
                    #pragma unroll
                    for (int g = 0; g < 4; ++g) acc[bb2][g] += wx[g][i] * xv;
                }
                const float4* h4 = (const float4*)(&h1buf[prv][b][0]);
                #pragma unroll
                for (int c4 = 0; c4 < 9; ++c4) {
                    const float4 hv = h4[c4];
                    #pragma unroll
                    for (int g = 0; g < 4; ++g) {
                        acc[bb2][g] += w[g][4*c4+0] * hv.x;
                        acc[bb2][g] += w[g][4*c4+1] * hv.y;
                        acc[bb2][g] += w[g][4*c4+2] * hv.z;
                        acc[bb2][g] += w[g][4*c4+3] * hv.w;
                    }
                }
                const float h36 = h1buf[prv][b][36];
                const float h37 = h1buf[prv][b][37];
                #pragma unroll
                for (int g = 0; g < 4; ++g) {
                    acc[bb2][g] += w[g][36] * h36;
                    acc[bb2][g] += w[g][37] * h37;
                }
            }
            #pragma unroll
            for (int bb2 = 0; bb2 < 2; ++bb2) {
                const int b  = bp * 2 + bb2;
                const float ig = fsig(acc[bb2][0]);
                const float fg = fsig(acc[bb2][1]);
                const float gg = ftanh(acc[bb2][2]);
                const float og = fsig(acc[bb2][3]);
                const float c  = fg * cst[bb2] + ig * gg;
                cst[bb2] = c;
                h1buf[cur][b][u] = og * ftanh(c);
            }
        } else if (role == 2) {
            // layer 2 recurrent part: q = Whh1 @ h2(t-1)  (independent of h1(t))
            float acc[2][4];
            #pragma unroll
            for (int bb2 = 0; bb2 < 2; ++bb2) {
                const int b = bp * 2 + bb2;
                #pragma unroll
                for (int g = 0; g < 4; ++g) acc[bb2][g] = 0.0f;
                const float4* h4 = (const float4*)(&h2buf[prv][b][0]);
                #pragma unroll
                for (int c4 = 0; c4 < 9; ++c4) {
                    const float4 hv = h4[c4];
                    #pragma unroll
                    for (int g = 0; g < 4; ++g) {
                        acc[bb2][g] += w[g][4*c4+0] * hv.x;
                        acc[bb2][g] += w[g][4*c4+1] * hv.y;
                        acc[bb2][g] += w[g][4*c4+2] * hv.z;
                        acc[bb2][g] += w[g][4*c4+3] * hv.w;
                    }
                }
                const float h36 = h2buf[prv][b][36];
                const float h37 = h2buf[prv][b][37];
                #pragma unroll
                for (int g = 0; g < 4; ++g) {
                    acc[bb2][g] += w[g][36] * h36;
                    acc[bb2][g] += w[g][37] * h37;
                }
                #pragma unroll
                for (int g = 0; g < 4; ++g) qbuf[b][u + g * NH] = acc[bb2][g];
            }
        } else if (role == 3) {
            // prefetch x(t+1) into the other slot
            const int s = tid - 3 * NG;
            const int b = s / NI, i = s % NI;
            if (t + 1 < TT)
                xbuf[prv][b][i] = x[((size_t)(bbase + b) * TT + (t + 1)) * NI + i];
        }
        __syncthreads();

        // ---------------- phase 2 ----------------
        if (role == 1) {
            // layer 2: g = b1 + Wih1 h1(t) + q; then pointwise
            float acc[2][4];
            #pragma unroll
            for (int bb2 = 0; bb2 < 2; ++bb2) {
                const int b = bp * 2 + bb2;
                #pragma unroll
                for (int g = 0; g < 4; ++g) acc[bb2][g] = bias[g] + qbuf[b][u + g * NH];
                const float4* h4 = (const float4*)(&h1buf[cur][b][0]);
                #pragma unroll
                for (int c4 = 0; c4 < 9; ++c4) {
                    const float4 hv = h4[c4];
                    #pragma unroll
                    for (int g = 0; g < 4; ++g) {
                        acc[bb2][g] += w[g][4*c4+0] * hv.x;
                        acc[bb2][g] += w[g][4*c4+1] * hv.y;
                        acc[bb2][g] += w[g][4*c4+2] * hv.z;
                        acc[bb2][g] += w[g][4*c4+3] * hv.w;
                    }
                }
                const float h36 = h1buf[cur][b][36];
                const float h37 = h1buf[cur][b][37];
                #pragma unroll
                for (int g = 0; g < 4; ++g) {
                    acc[bb2][g] += w[g][36] * h36;
                    acc[bb2][g] += w[g][37] * h37;
                }
                const float ig = fsig(acc[bb2][0]);
                const float fg = fsig(acc[bb2][1]);
                const float gg = ftanh(acc[bb2][2]);
                const float og = fsig(acc[bb2][3]);
                const float c  = fg * cst[bb2] + ig * gg;
                cst[bb2] = c;
                h2buf[cur][b][u] = og * ftanh(c);
            }
        }
        __syncthreads();
    }

    // epilogue: out = h2(T-1) @ Wc.T + bc ; final h2 lives in slot (TT-1)&1 == 1
    if (tid < NB * NCLS) {
        const int b = tid / NCLS, c = tid % NCLS;
        float acc = bc[c];
        #pragma unroll
        for (int k = 0; k < NH; ++k) acc += Wc[c * NH + k] * h2buf[1][b][k];
        out[(size_t)(bbase + b) * NCLS + c] = acc;
    }
}

extern "C" void kernel_launch(void* const* d_in, const int* in_sizes, int n_in,
                              void* d_out, int out_size, void* d_ws, size_t ws_size,
                              hipStream_t stream) {
    const float* x    = (const float*)d_in[0];
    const float* Wih0 = (const float*)d_in[1];
    const float* Whh0 = (const float*)d_in[2];
    const float* b0   = (const float*)d_in[3];
    const float* Wih1 = (const float*)d_in[4];
    const float* Whh1 = (const float*)d_in[5];
    const float* b1   = (const float*)d_in[6];
    const float* Wc   = (const float*)d_in[7];
    const float* bc   = (const float*)d_in[8];
    float* out = (float*)d_out;

    dim3 grid(BATCH / NB);
    dim3 block(BLK);
    hipLaunchKernelGGL(lstm2_kernel, grid, block, 0, stream,
                       x, Wih0, Whh0, b0, Wih1, Whh1, b1, Wc, bc, out);
}